// Round 1
// baseline (163.487 us; speedup 1.0000x reference)
//
#include <hip/hip_runtime.h>
#include <math.h>

#define BB 32
#define CC 1024
#define NN 4096

// ---------------------------------------------------------------------------
// Kernel A: copy x -> out0 (float4 vectorized, fully coalesced)
// ---------------------------------------------------------------------------
__global__ __launch_bounds__(256) void copy_x_kernel(const float4* __restrict__ src,
                                                     float4* __restrict__ dst, int n4) {
    int i = blockIdx.x * blockDim.x + threadIdx.x;
    if (i < n4) dst[i] = src[i];
}

// ---------------------------------------------------------------------------
// Kernel B: per-(b,c) argmax over n of W[c]·x[b,:,n], then counts[b,argmax]++ .
// grid = 32 b * 8 channel-groups = 256 blocks, 256 threads.
// Each block stages x[b] (3*4096 f32 = 48KB) in LDS; 2 threads per channel,
// each scanning one half of n; pair combine keeps first-index tie-break.
// ---------------------------------------------------------------------------
__global__ __launch_bounds__(256) void argmax_counts(const float* __restrict__ x,
                                                     const float* __restrict__ W,
                                                     float* __restrict__ counts) {
    __shared__ float xs[3 * NN];
    __shared__ float bv[256];
    __shared__ int   bi[256];
    const int b   = blockIdx.x >> 3;
    const int g   = blockIdx.x & 7;
    const int tid = threadIdx.x;

    // stage x[b] into LDS, coalesced float4
    {
        const float4* src = (const float4*)(x + (size_t)b * 3 * NN);
        float4* dst = (float4*)xs;
        #pragma unroll
        for (int i = 0; i < (3 * NN / 4) / 256; ++i)
            dst[tid + i * 256] = src[tid + i * 256];
    }
    __syncthreads();

    const int c    = g * 128 + (tid >> 1);
    const int half = tid & 1;
    const float w0 = W[c * 3 + 0];
    const float w1 = W[c * 3 + 1];
    const float w2 = W[c * 3 + 2];

    float best = -INFINITY;
    int bidx = 0;
    const int n0 = half * (NN / 2);
    // Only 2 distinct LDS addresses per wave per read -> broadcast, no conflicts.
    for (int n = n0; n < n0 + NN / 2; n += 4) {
        float4 a0 = *(const float4*)(xs + n);
        float4 a1 = *(const float4*)(xs + NN + n);
        float4 a2 = *(const float4*)(xs + 2 * NN + n);
        float v;
        // fma chain mimics FMA-contracted reference accumulation order d=0,1,2
        v = fmaf(w2, a2.x, fmaf(w1, a1.x, w0 * a0.x)); if (v > best) { best = v; bidx = n;     }
        v = fmaf(w2, a2.y, fmaf(w1, a1.y, w0 * a0.y)); if (v > best) { best = v; bidx = n + 1; }
        v = fmaf(w2, a2.z, fmaf(w1, a1.z, w0 * a0.z)); if (v > best) { best = v; bidx = n + 2; }
        v = fmaf(w2, a2.w, fmaf(w1, a1.w, w0 * a0.w)); if (v > best) { best = v; bidx = n + 3; }
    }
    bv[tid] = best;
    bi[tid] = bidx;
    __syncthreads();
    if (half == 0) {
        // strict > : half-0 (lower indices) wins ties -> first occurrence
        int winner = (bv[tid + 1] > best) ? bi[tid + 1] : bidx;
        atomicAdd(&counts[(size_t)b * NN + winner], 1.0f);
    }
}

// ---------------------------------------------------------------------------
// Kernel C: per-row (block per b): entropy + stable ascending argsort of counts
// via counting sort (values in [0,1024]).
// ---------------------------------------------------------------------------
__global__ __launch_bounds__(256) void sort_entropy(const float* __restrict__ counts,
                                                    float* __restrict__ imp2,
                                                    float* __restrict__ ent) {
    __shared__ int   cv[NN];          // counts as int
    __shared__ int   hist[CC + 1];
    __shared__ int   cur[CC + 1];     // running output cursor per value
    __shared__ int   partial[256];
    __shared__ float red[256];

    const int b   = blockIdx.x;
    const int tid = threadIdx.x;
    const float* row = counts + (size_t)b * NN;

    // load row, convert to int, accumulate per-thread sum of (count + eps)
    float s_local = 0.f;
    int zloc = 0, oloc = 0;
    for (int v = tid; v <= CC; v += 256) hist[v] = 0;
    __syncthreads();
    for (int n = tid; n < NN; n += 256) {
        float f = row[n];
        int ci = (int)(f + 0.5f);
        cv[n] = ci;
        s_local += f + 1e-6f;
        // avoid massive same-address LDS atomic serialization for the
        // dominant values 0 and 1 (Poisson(0.25) occupancy)
        if (ci == 0)      zloc++;
        else if (ci == 1) oloc++;
        else              atomicAdd(&hist[ci], 1);
    }
    if (zloc) atomicAdd(&hist[0], zloc);
    if (oloc) atomicAdd(&hist[1], oloc);
    __syncthreads();

    // exclusive prefix scan of hist[0..1023]: groups of 4 + Hillis-Steele
    int h0 = hist[4 * tid + 0], h1 = hist[4 * tid + 1];
    int h2 = hist[4 * tid + 2], h3 = hist[4 * tid + 3];
    int s4 = h0 + h1 + h2 + h3;
    partial[tid] = s4;
    __syncthreads();
    for (int off = 1; off < 256; off <<= 1) {
        int v   = partial[tid];
        int add = (tid >= off) ? partial[tid - off] : 0;
        __syncthreads();
        partial[tid] = v + add;
        __syncthreads();
    }
    int excl = (tid > 0) ? partial[tid - 1] : 0;
    cur[4 * tid + 0] = excl;            excl += h0;
    cur[4 * tid + 1] = excl;            excl += h1;
    cur[4 * tid + 2] = excl;            excl += h2;
    cur[4 * tid + 3] = excl;
    if (tid == 0) cur[CC] = NN - hist[CC];
    __syncthreads();

    // ---- entropy: S = sum(counts + eps); ent = -sum(p log2 p)/log2(N)
    red[tid] = s_local;
    __syncthreads();
    for (int off = 128; off > 0; off >>= 1) {
        if (tid < off) red[tid] += red[tid + off];
        __syncthreads();
    }
    float S = red[0];
    __syncthreads();   // everyone has read red[0] before reuse
    float e_local = 0.f;
    for (int n = tid; n < NN; n += 256) {
        float p = ((float)cv[n] + 1e-6f) / S;
        e_local += p * log2f(p);
    }
    red[tid] = e_local;
    __syncthreads();
    for (int off = 128; off > 0; off >>= 1) {
        if (tid < off) red[tid] += red[tid + off];
        __syncthreads();
    }
    if (tid == 0) ent[b] = -red[0] / 12.0f;   // log2(4096) = 12 exact
    __syncthreads();

    // ---- stable placement: 16 chunks of 256 in index order.
    // rank within chunk among equal values via LDS broadcast compares (j<tid),
    // then advance cur[v] with per-thread LDS atomics between barriers.
    float* out_row = imp2 + (size_t)b * NN;
    for (int k = 0; k < 16; ++k) {
        const int bn = k * 256;
        int v = cv[bn + tid];
        int rank = 0;
        for (int j = 0; j < tid; ++j)
            rank += (cv[bn + j] == v);
        int pos = cur[v] + rank;
        out_row[pos] = (float)(bn + tid);
        __syncthreads();             // all cur[] reads done
        atomicAdd(&cur[v], 1);
        __syncthreads();             // cur[] updated for next chunk
    }
}

extern "C" void kernel_launch(void* const* d_in, const int* in_sizes, int n_in,
                              void* d_out, int out_size, void* d_ws, size_t ws_size,
                              hipStream_t stream) {
    const float* x = (const float*)d_in[0];   // [32,3,4096]
    const float* W = (const float*)d_in[1];   // [1024,3]
    float* out    = (float*)d_out;
    float* out_x  = out;                       // 393216
    float* counts = out + (size_t)BB * 3 * NN; // 131072
    float* imp2   = counts + (size_t)BB * NN;  // 131072
    float* ent    = imp2 + (size_t)BB * NN;    // 32

    // counts is accumulated with atomics -> must start at zero (d_out poisoned)
    hipMemsetAsync(counts, 0, (size_t)BB * NN * sizeof(float), stream);

    copy_x_kernel<<<(BB * 3 * NN / 4) / 256, 256, 0, stream>>>(
        (const float4*)x, (float4*)out_x, BB * 3 * NN / 4);
    argmax_counts<<<BB * 8, 256, 0, stream>>>(x, W, counts);
    sort_entropy<<<BB, 256, 0, stream>>>(counts, imp2, ent);
}

// Round 2
// 103.153 us; speedup vs baseline: 1.5849x; 1.5849x over previous
//
#include <hip/hip_runtime.h>
#include <math.h>

#define BB 32
#define CC 1024
#define NN 4096
#define NCH 16          // n-chunks per row
#define CHK 256         // points per chunk

typedef unsigned long long u64;

// Monotone float encoding: key order == (value asc, then smaller index wins on tie
// via larger (4095-idx)). All finite floats map to mono > 0.
__device__ __forceinline__ u64 enc_key(float v, int gidx) {
    unsigned u = __float_as_uint(v);
    unsigned mono = (u & 0x80000000u) ? ~u : (u | 0x80000000u);
    return ((u64)mono << 12) | (unsigned)(4095 - gidx);
}

// ---------------------------------------------------------------------------
// K1: per-(b,chunk) partial argmax over 1024 channels; also copies x->out_x
// and zero-inits counts. grid = 32*16 = 512 blocks, 256 threads, 4 ch/thread.
// ---------------------------------------------------------------------------
__global__ __launch_bounds__(256) void k1_argmax_partial(
    const float* __restrict__ x, const float* __restrict__ W,
    float* __restrict__ out_x, float* __restrict__ counts,
    u64* __restrict__ pkeys) {
    __shared__ float xs[3 * CHK];
    const int bid = blockIdx.x;
    const int b = bid >> 4, k = bid & 15;
    const int tid = threadIdx.x;

    // zero counts: 512*256 threads == 131072 == BB*NN exactly (used by K2 atomics)
    counts[(bid << 8) | tid] = 0.0f;

    // stage x[b][:, k*256 .. k*256+255] into LDS and copy through to out_x
    if (tid < 192) {
        int d = tid >> 6;                 // dim 0..2
        int off = (tid & 63) << 2;        // 0..252
        const float* src = x + (size_t)(b * 3 + d) * NN + k * CHK + off;
        float4 v = *(const float4*)src;
        *(float4*)(xs + d * CHK + off) = v;
        *(float4*)(out_x + (size_t)(b * 3 + d) * NN + k * CHK + off) = v;
    }
    __syncthreads();

    float w0[4], w1[4], w2[4];
    #pragma unroll
    for (int q = 0; q < 4; ++q) {
        int c = tid + q * 256;
        w0[q] = W[c * 3 + 0];
        w1[q] = W[c * 3 + 1];
        w2[q] = W[c * 3 + 2];
    }
    float best[4] = {-INFINITY, -INFINITY, -INFINITY, -INFINITY};
    int bidx[4] = {0, 0, 0, 0};
    #pragma unroll 4
    for (int n = 0; n < CHK; ++n) {
        float x0 = xs[n], x1 = xs[CHK + n], x2 = xs[2 * CHK + n];  // LDS broadcast
        #pragma unroll
        for (int q = 0; q < 4; ++q) {
            // identical fp contraction to round-1 kernel (bit-matched reference)
            float v = fmaf(w2[q], x2, fmaf(w1[q], x1, w0[q] * x0));
            if (v > best[q]) { best[q] = v; bidx[q] = n; }  // strict > = first index
        }
    }
    #pragma unroll
    for (int q = 0; q < 4; ++q) {
        int c = tid + q * 256;
        pkeys[(size_t)(b * NCH + k) * CC + c] = enc_key(best[q], k * CHK + bidx[q]);
    }
}

// ---------------------------------------------------------------------------
// K2: combine 16 partial keys per (b,c) -> winning index -> counts atomicAdd.
// Also zero-inits G (row histograms). grid = 129 blocks x 256.
// ---------------------------------------------------------------------------
__global__ __launch_bounds__(256) void k2_combine_count(
    const u64* __restrict__ pkeys, float* __restrict__ counts,
    int* __restrict__ G) {
    int t = blockIdx.x * 256 + threadIdx.x;
    if (t < BB * (CC + 1)) G[t] = 0;          // 32*1025 = 32800
    if (t < BB * CC) {
        int b = t >> 10, c = t & 1023;
        u64 best = 0;
        #pragma unroll
        for (int k = 0; k < NCH; ++k) {
            u64 key = pkeys[(size_t)(b * NCH + k) * CC + c];
            best = (key > best) ? key : best;  // max key = max value, first index
        }
        int idx = 4095 - (int)(best & 0xFFFu);
        atomicAdd(&counts[b * NN + idx], 1.0f);
    }
}

// ---------------------------------------------------------------------------
// K3a: per-(b,chunk) histogram of count values (0..1024) -> H, and atomic
// accumulate into row histogram G. grid = 512 blocks x 256.
// ---------------------------------------------------------------------------
__global__ __launch_bounds__(256) void k3a_chunk_hist(
    const float* __restrict__ counts, int* __restrict__ H, int* __restrict__ G) {
    __shared__ int hist[CC + 1];
    const int bid = blockIdx.x;
    const int b = bid >> 4, k = bid & 15;
    const int tid = threadIdx.x;

    for (int v = tid; v <= CC; v += 256) hist[v] = 0;
    __syncthreads();

    int ci = (int)(counts[(size_t)b * NN + k * CHK + tid] + 0.5f);
    // values are Poisson(0.25): ~78% are 0, ~19% are 1 -> ballot-aggregate those
    u64 m0 = __ballot(ci == 0);
    u64 m1 = __ballot(ci == 1);
    if ((tid & 63) == 0) {
        if (m0) atomicAdd(&hist[0], (int)__popcll(m0));
        if (m1) atomicAdd(&hist[1], (int)__popcll(m1));
    }
    if (ci > 1) atomicAdd(&hist[ci], 1);
    __syncthreads();

    for (int v = tid; v <= CC; v += 256) {
        int h = hist[v];
        H[(size_t)(b * NCH + k) * (CC + 1) + v] = h;   // coalesced write
        if (h) atomicAdd(&G[b * (CC + 1) + v], h);     // ~7 nonzero bins/block
    }
}

// ---------------------------------------------------------------------------
// K3b: per-row exclusive scan of G -> cum, plus entropy from histogram.
// grid = 32 blocks x 256.
// ---------------------------------------------------------------------------
__global__ __launch_bounds__(256) void k3b_scan_entropy(
    const int* __restrict__ G, int* __restrict__ cum, float* __restrict__ ent) {
    __shared__ int partial[256];
    __shared__ float red[256];
    const int b = blockIdx.x;
    const int tid = threadIdx.x;
    const int* g = G + b * (CC + 1);
    int* cm = cum + b * (CC + 1);

    int h0 = g[4 * tid + 0], h1 = g[4 * tid + 1];
    int h2 = g[4 * tid + 2], h3 = g[4 * tid + 3];
    partial[tid] = h0 + h1 + h2 + h3;
    __syncthreads();
    for (int off = 1; off < 256; off <<= 1) {
        int v = partial[tid];
        int add = (tid >= off) ? partial[tid - off] : 0;
        __syncthreads();
        partial[tid] = v + add;
        __syncthreads();
    }
    int excl = (tid > 0) ? partial[tid - 1] : 0;
    cm[4 * tid + 0] = excl;  excl += h0;
    cm[4 * tid + 1] = excl;  excl += h1;
    cm[4 * tid + 2] = excl;  excl += h2;
    cm[4 * tid + 3] = excl;
    if (tid == 0) cm[CC] = NN - g[CC];

    // entropy: sum over n of p*log2(p) == sum over v of G[v]*p_v*log2(p_v)
    // S = sum(counts + eps) = 1024 + 4096*1e-6 exactly (sum of counts == C)
    const float S = 1024.0f + 4096.0f * 1e-6f;
    float e = 0.f;
    for (int v = tid; v <= CC; v += 256) {
        int h = g[v];
        if (h) {
            float p = ((float)v + 1e-6f) / S;
            e += (float)h * p * log2f(p);
        }
    }
    red[tid] = e;
    __syncthreads();
    for (int off = 128; off > 0; off >>= 1) {
        if (tid < off) red[tid] += red[tid + off];
        __syncthreads();
    }
    if (tid == 0) ent[b] = -red[0] / 12.0f;   // log2(4096) = 12
}

// ---------------------------------------------------------------------------
// K4: per-(b,chunk) stable placement. pos = cum_excl[v] + sum_{k'<k} H[k'][v]
//     + rank among equals within chunk. grid = 512 blocks x 256.
// ---------------------------------------------------------------------------
__global__ __launch_bounds__(256) void k4_place(
    const float* __restrict__ counts, const int* __restrict__ H,
    const int* __restrict__ cum, float* __restrict__ imp2) {
    __shared__ int cvs[CHK];
    const int bid = blockIdx.x;
    const int b = bid >> 4, k = bid & 15;
    const int tid = threadIdx.x;
    const int n = k * CHK + tid;

    int ci = (int)(counts[(size_t)b * NN + n] + 0.5f);
    cvs[tid] = ci;
    __syncthreads();

    int rank = 0;
    #pragma unroll 8
    for (int j = 0; j < CHK - 1; ++j) {        // LDS broadcast reads
        int w = cvs[j];
        rank += (j < tid && w == ci) ? 1 : 0;
    }
    int pref = 0;
    for (int k2 = 0; k2 < k; ++k2)             // k is block-uniform
        pref += H[(size_t)(b * NCH + k2) * (CC + 1) + ci];

    int pos = cum[b * (CC + 1) + ci] + pref + rank;
    imp2[(size_t)b * NN + pos] = (float)n;
}

extern "C" void kernel_launch(void* const* d_in, const int* in_sizes, int n_in,
                              void* d_out, int out_size, void* d_ws, size_t ws_size,
                              hipStream_t stream) {
    const float* x = (const float*)d_in[0];    // [32,3,4096]
    const float* W = (const float*)d_in[1];    // [1024,3]
    float* out    = (float*)d_out;
    float* out_x  = out;                        // 393216
    float* counts = out + (size_t)BB * 3 * NN;  // 131072
    float* imp2   = counts + (size_t)BB * NN;   // 131072
    float* ent    = imp2 + (size_t)BB * NN;     // 32

    // workspace layout
    u64* pkeys = (u64*)d_ws;                                  // 32*16*1024 u64 = 4 MB
    int* G     = (int*)(pkeys + (size_t)BB * NCH * CC);       // 32*1025 = 131 KB
    int* H     = G + BB * (CC + 1);                           // 32*16*1025 = 2.1 MB
    int* cum   = H + (size_t)BB * NCH * (CC + 1);             // 32*1025 = 131 KB

    k1_argmax_partial<<<BB * NCH, 256, 0, stream>>>(x, W, out_x, counts, pkeys);
    k2_combine_count<<<129, 256, 0, stream>>>(pkeys, counts, G);
    k3a_chunk_hist<<<BB * NCH, 256, 0, stream>>>(counts, H, G);
    k3b_scan_entropy<<<BB, 256, 0, stream>>>(G, cum, ent);
    k4_place<<<BB * NCH, 256, 0, stream>>>(counts, H, cum, imp2);
}

// Round 3
// 88.750 us; speedup vs baseline: 1.8421x; 1.1623x over previous
//
#include <hip/hip_runtime.h>
#include <math.h>

#define BB 32
#define CC 1024
#define NN 4096
#define NCH 16          // n-chunks per row
#define CHK 256         // points per chunk

typedef unsigned long long u64;

// Monotone float encoding: key order == (value asc, smaller index wins ties via
// larger (4095-idx)). All finite floats map to mono > 0.
__device__ __forceinline__ u64 enc_key(float v, int gidx) {
    unsigned u = __float_as_uint(v);
    unsigned mono = (u & 0x80000000u) ? ~u : (u | 0x80000000u);
    return ((u64)mono << 12) | (unsigned)(4095 - gidx);
}

// ---------------------------------------------------------------------------
// K1: per-(b,chunk) partial argmax over 1024 channels (4 per thread) + copy of
// the x chunk to out_x. No LDS: x-chunk addresses are wave-uniform -> scalar /
// L1-broadcast loads. Group-of-4 max trick: one cmp+select per 4 points;
// winner's in-group position resolved by bit-exact recompute at the end.
// grid = 32*16 = 512 blocks x 256 threads.
// ---------------------------------------------------------------------------
__global__ __launch_bounds__(256) void k1_argmax_partial(
    const float* __restrict__ x, const float* __restrict__ W,
    float* __restrict__ out_x, u64* __restrict__ pkeys) {
    const int bid = blockIdx.x;
    const int b = bid >> 4, k = bid & 15;
    const int tid = threadIdx.x;

    // copy chunk through to out_x (3 dims x 256 floats = 192 float4)
    if (tid < 192) {
        int d = tid >> 6;
        int off = (tid & 63) << 2;
        const size_t p = (size_t)(b * 3 + d) * NN + k * CHK + off;
        *(float4*)(out_x + p) = *(const float4*)(x + p);
    }

    float w0[4], w1[4], w2[4];
    #pragma unroll
    for (int q = 0; q < 4; ++q) {
        int c = q * 256 + tid;
        w0[q] = W[c * 3 + 0];
        w1[q] = W[c * 3 + 1];
        w2[q] = W[c * 3 + 2];
    }

    const float* xb = x + (size_t)b * 3 * NN + k * CHK;
    float best[4] = {-INFINITY, -INFINITY, -INFINITY, -INFINITY};
    int gn[4] = {0, 0, 0, 0};

    #pragma unroll 4
    for (int n = 0; n < CHK; n += 4) {
        // wave-uniform addresses -> scalar-cache loads
        float4 a0 = *(const float4*)(xb + n);
        float4 a1 = *(const float4*)(xb + NN + n);
        float4 a2 = *(const float4*)(xb + 2 * NN + n);
        #pragma unroll
        for (int q = 0; q < 4; ++q) {
            // identical fp contraction to round-1/2 kernels (bit-matched ref)
            float v0 = fmaf(w2[q], a2.x, fmaf(w1[q], a1.x, w0[q] * a0.x));
            float v1 = fmaf(w2[q], a2.y, fmaf(w1[q], a1.y, w0[q] * a0.y));
            float v2 = fmaf(w2[q], a2.z, fmaf(w1[q], a1.z, w0[q] * a0.z));
            float v3 = fmaf(w2[q], a2.w, fmaf(w1[q], a1.w, w0[q] * a0.w));
            float gm = fmaxf(fmaxf(v0, v1), fmaxf(v2, v3));   // exact
            if (gm > best[q]) { best[q] = gm; gn[q] = n; }    // first group wins ties
        }
    }

    // resolve position within winning group (bit-exact recompute)
    #pragma unroll
    for (int q = 0; q < 4; ++q) {
        int n = gn[q];
        float4 a0 = *(const float4*)(xb + n);
        float4 a1 = *(const float4*)(xb + NN + n);
        float4 a2 = *(const float4*)(xb + 2 * NN + n);
        float v0 = fmaf(w2[q], a2.x, fmaf(w1[q], a1.x, w0[q] * a0.x));
        float v1 = fmaf(w2[q], a2.y, fmaf(w1[q], a1.y, w0[q] * a0.y));
        float v2 = fmaf(w2[q], a2.z, fmaf(w1[q], a1.z, w0[q] * a0.z));
        int j = (v0 == best[q]) ? 0 : (v1 == best[q]) ? 1 : (v2 == best[q]) ? 2 : 3;
        pkeys[(size_t)(b * NCH + k) * CC + q * 256 + tid] =
            enc_key(best[q], k * CHK + n + j);
    }
}

// ---------------------------------------------------------------------------
// K2: per-row mega-kernel. grid = 32 blocks x 1024 threads.
// combine partial keys -> counts (LDS hist, no global atomics) -> per-chunk
// hists H[16][1025] -> row scan -> entropy -> cumP table for placement.
// ---------------------------------------------------------------------------
__global__ __launch_bounds__(1024) void k2_row(
    const u64* __restrict__ pkeys, float* __restrict__ counts,
    int* __restrict__ cumP, float* __restrict__ ent) {
    __shared__ int cnt[NN];             // 16 KB
    __shared__ int H[NCH * (CC + 1)];   // 65.6 KB
    __shared__ int sc[1024];            // 4 KB
    __shared__ float red[1024];         // 4 KB
    __shared__ int exv[CC + 1];         // 4.1 KB

    const int b = blockIdx.x;
    const int tid = threadIdx.x;
    const int wv = tid >> 6, lane = tid & 63;

    #pragma unroll
    for (int i = 0; i < 4; ++i) cnt[tid + i * 1024] = 0;
    for (int i = tid; i < NCH * (CC + 1); i += 1024) H[i] = 0;
    __syncthreads();

    // combine 16 partial keys for channel c = tid -> winner index -> LDS hist
    {
        u64 bestk = 0;
        const u64* pk = pkeys + (size_t)b * NCH * CC + tid;
        #pragma unroll
        for (int k = 0; k < NCH; ++k) {
            u64 key = pk[k * CC];
            bestk = (key > bestk) ? key : bestk;
        }
        int idx = 4095 - (int)(bestk & 0xFFFu);
        atomicAdd(&cnt[idx], 1);
    }
    __syncthreads();

    // write counts (coalesced float4) + per-chunk hist (wave w <-> chunk w)
    {
        float4 cf;
        cf.x = (float)cnt[4 * tid + 0];
        cf.y = (float)cnt[4 * tid + 1];
        cf.z = (float)cnt[4 * tid + 2];
        cf.w = (float)cnt[4 * tid + 3];
        *(float4*)(counts + (size_t)b * NN + 4 * tid) = cf;

        int h0 = 0, h1 = 0;
        #pragma unroll
        for (int r = 0; r < 4; ++r) {
            int ci = cnt[wv * CHK + r * 64 + lane];
            u64 m0 = __ballot(ci == 0);
            u64 m1 = __ballot(ci == 1);
            if (lane == 0) { h0 += (int)__popcll(m0); h1 += (int)__popcll(m1); }
            if (ci > 1) atomicAdd(&H[wv * (CC + 1) + ci], 1);
        }
        if (lane == 0) {    // bins 0/1 only ever written by this wave's lane 0
            H[wv * (CC + 1) + 0] = h0;
            H[wv * (CC + 1) + 1] = h1;
        }
    }
    __syncthreads();

    // row histogram G[v] for v = tid, then exclusive scan (Hillis-Steele)
    int g_v = 0;
    #pragma unroll
    for (int w = 0; w < NCH; ++w) g_v += H[w * (CC + 1) + tid];
    sc[tid] = g_v;
    __syncthreads();
    for (int off = 1; off < 1024; off <<= 1) {
        int v = sc[tid];
        int add = (tid >= off) ? sc[tid - off] : 0;
        __syncthreads();
        sc[tid] = v + add;
        __syncthreads();
    }
    exv[tid] = (tid > 0) ? sc[tid - 1] : 0;
    if (tid == 0) exv[CC] = sc[1023];   // = NN - G[1024]
    __syncthreads();

    // cumP[b][k][v] = cum_excl[v] + sum_{k'<k} H[k'][v]
    {
        int run = exv[tid];
        int* cp = cumP + (size_t)b * NCH * (CC + 1) + tid;
        #pragma unroll
        for (int k = 0; k < NCH; ++k) {
            cp[k * (CC + 1)] = run;
            run += H[k * (CC + 1) + tid];
        }
        if (tid == 0) {
            int run2 = exv[CC];
            int* cp2 = cumP + (size_t)b * NCH * (CC + 1) + CC;
            for (int k = 0; k < NCH; ++k) {
                cp2[k * (CC + 1)] = run2;
                run2 += H[k * (CC + 1) + CC];
            }
        }
    }

    // entropy: sum over v of G[v] * p log2 p, p=(v+eps)/S, S = 1024 + 4096*eps
    const float S = 1024.0f + 4096.0f * 1e-6f;
    float e = 0.f;
    if (g_v) {
        float p = ((float)tid + 1e-6f) / S;
        e = (float)g_v * p * log2f(p);
    }
    if (tid == 0) {
        int g1024 = 0;
        #pragma unroll
        for (int w = 0; w < NCH; ++w) g1024 += H[w * (CC + 1) + CC];
        if (g1024) {
            float p = (1024.0f + 1e-6f) / S;
            e += (float)g1024 * p * log2f(p);
        }
    }
    red[tid] = e;
    __syncthreads();
    for (int off = 512; off > 0; off >>= 1) {
        if (tid < off) red[tid] += red[tid + off];
        __syncthreads();
    }
    if (tid == 0) ent[b] = -red[0] / 12.0f;   // log2(4096) = 12
}

// ---------------------------------------------------------------------------
// K3: stable placement. pos = cumP[b][k][v] + rank among equals within chunk.
// grid = 512 blocks x 256 threads.
// ---------------------------------------------------------------------------
__global__ __launch_bounds__(256) void k3_place(
    const float* __restrict__ counts, const int* __restrict__ cumP,
    float* __restrict__ imp2) {
    __shared__ int cvs[CHK];
    const int bid = blockIdx.x;
    const int b = bid >> 4, k = bid & 15;
    const int tid = threadIdx.x;
    const int n = k * CHK + tid;

    int ci = (int)(counts[(size_t)b * NN + n] + 0.5f);
    cvs[tid] = ci;
    __syncthreads();

    int rank = 0;
    #pragma unroll 8
    for (int j = 0; j < CHK - 1; ++j)          // LDS broadcast reads
        rank += (j < tid && cvs[j] == ci) ? 1 : 0;

    int pos = cumP[(size_t)(b * NCH + k) * (CC + 1) + ci] + rank;
    imp2[(size_t)b * NN + pos] = (float)n;
}

extern "C" void kernel_launch(void* const* d_in, const int* in_sizes, int n_in,
                              void* d_out, int out_size, void* d_ws, size_t ws_size,
                              hipStream_t stream) {
    const float* x = (const float*)d_in[0];    // [32,3,4096]
    const float* W = (const float*)d_in[1];    // [1024,3]
    float* out    = (float*)d_out;
    float* out_x  = out;                        // 393216
    float* counts = out + (size_t)BB * 3 * NN;  // 131072
    float* imp2   = counts + (size_t)BB * NN;   // 131072
    float* ent    = imp2 + (size_t)BB * NN;     // 32

    u64* pkeys = (u64*)d_ws;                               // 32*16*1024 u64 = 4 MB
    int* cumP  = (int*)(pkeys + (size_t)BB * NCH * CC);    // 32*16*1025 int = 2.1 MB

    k1_argmax_partial<<<BB * NCH, 256, 0, stream>>>(x, W, out_x, pkeys);
    k2_row<<<BB, 1024, 0, stream>>>(pkeys, counts, cumP, ent);
    k3_place<<<BB * NCH, 256, 0, stream>>>(counts, cumP, imp2);
}

// Round 4
// 79.770 us; speedup vs baseline: 2.0495x; 1.1126x over previous
//
#include <hip/hip_runtime.h>
#include <math.h>

#define BB 32
#define CC 1024
#define NN 4096
#define NCH 16          // n-chunks per row
#define CHK 256         // points per chunk

typedef unsigned long long u64;

// Monotone float encoding: key order == (value asc, smaller index wins ties via
// larger (4095-idx)). All finite floats map to mono > 0.
__device__ __forceinline__ u64 enc_key(float v, int gidx) {
    unsigned u = __float_as_uint(v);
    unsigned mono = (u & 0x80000000u) ? ~u : (u | 0x80000000u);
    return ((u64)mono << 12) | (unsigned)(4095 - gidx);
}

// ---------------------------------------------------------------------------
// K1: per-(b,chunk) partial argmax over 1024 channels (4 per thread) + copy of
// the x chunk to out_x. Wave-uniform x addresses -> scalar/L1-broadcast loads.
// Group-of-4 max trick; winner position resolved by bit-exact recompute.
// grid = 32*16 = 512 blocks x 256 threads. (unchanged from round 3, verified)
// ---------------------------------------------------------------------------
__global__ __launch_bounds__(256) void k1_argmax_partial(
    const float* __restrict__ x, const float* __restrict__ W,
    float* __restrict__ out_x, u64* __restrict__ pkeys) {
    const int bid = blockIdx.x;
    const int b = bid >> 4, k = bid & 15;
    const int tid = threadIdx.x;

    if (tid < 192) {
        int d = tid >> 6;
        int off = (tid & 63) << 2;
        const size_t p = (size_t)(b * 3 + d) * NN + k * CHK + off;
        *(float4*)(out_x + p) = *(const float4*)(x + p);
    }

    float w0[4], w1[4], w2[4];
    #pragma unroll
    for (int q = 0; q < 4; ++q) {
        int c = q * 256 + tid;
        w0[q] = W[c * 3 + 0];
        w1[q] = W[c * 3 + 1];
        w2[q] = W[c * 3 + 2];
    }

    const float* xb = x + (size_t)b * 3 * NN + k * CHK;
    float best[4] = {-INFINITY, -INFINITY, -INFINITY, -INFINITY};
    int gn[4] = {0, 0, 0, 0};

    #pragma unroll 4
    for (int n = 0; n < CHK; n += 4) {
        float4 a0 = *(const float4*)(xb + n);
        float4 a1 = *(const float4*)(xb + NN + n);
        float4 a2 = *(const float4*)(xb + 2 * NN + n);
        #pragma unroll
        for (int q = 0; q < 4; ++q) {
            // identical fp contraction to rounds 1-3 (bit-matched reference)
            float v0 = fmaf(w2[q], a2.x, fmaf(w1[q], a1.x, w0[q] * a0.x));
            float v1 = fmaf(w2[q], a2.y, fmaf(w1[q], a1.y, w0[q] * a0.y));
            float v2 = fmaf(w2[q], a2.z, fmaf(w1[q], a1.z, w0[q] * a0.z));
            float v3 = fmaf(w2[q], a2.w, fmaf(w1[q], a1.w, w0[q] * a0.w));
            float gm = fmaxf(fmaxf(v0, v1), fmaxf(v2, v3));   // exact
            if (gm > best[q]) { best[q] = gm; gn[q] = n; }    // first group wins
        }
    }

    #pragma unroll
    for (int q = 0; q < 4; ++q) {
        int n = gn[q];
        float4 a0 = *(const float4*)(xb + n);
        float4 a1 = *(const float4*)(xb + NN + n);
        float4 a2 = *(const float4*)(xb + 2 * NN + n);
        float v0 = fmaf(w2[q], a2.x, fmaf(w1[q], a1.x, w0[q] * a0.x));
        float v1 = fmaf(w2[q], a2.y, fmaf(w1[q], a1.y, w0[q] * a0.y));
        float v2 = fmaf(w2[q], a2.z, fmaf(w1[q], a1.z, w0[q] * a0.z));
        int j = (v0 == best[q]) ? 0 : (v1 == best[q]) ? 1 : (v2 == best[q]) ? 2 : 3;
        pkeys[(size_t)(b * NCH + k) * CC + q * 256 + tid] =
            enc_key(best[q], k * CHK + n + j);
    }
}

// ---------------------------------------------------------------------------
// K2: per-row mega-kernel incl. placement. grid = 32 blocks x 1024 threads.
// combine -> counts hist (LDS) -> per-chunk hists -> shuffle scan -> entropy
// -> stable counting-sort placement via ballot match-any + per-chunk cursors.
// ~6 barriers total.
// ---------------------------------------------------------------------------
__global__ __launch_bounds__(1024) void k2_row_all(
    const u64* __restrict__ pkeys, float* __restrict__ counts,
    float* __restrict__ imp2, float* __restrict__ ent) {
    __shared__ int   cnt[NN];               // 16 KB: counts per point
    __shared__ int   H[NCH * (CC + 1)];     // 65.6 KB: hist -> chunk-prefix/cursor
    __shared__ int   exvs[CC + 1];          // 4.1 KB: exclusive value prefix
    __shared__ int   wsum[16];
    __shared__ float esum[16];

    const int b = blockIdx.x;
    const int tid = threadIdx.x;
    const int wv = tid >> 6, lane = tid & 63;

    // 1. zero
    #pragma unroll
    for (int i = 0; i < 4; ++i) cnt[tid + i * 1024] = 0;
    #pragma unroll
    for (int i = 0; i < 16; ++i) H[tid + i * 1024] = 0;   // 16384 of 16400
    if (tid < NCH * (CC + 1) - 16 * 1024) H[16 * 1024 + tid] = 0;
    __syncthreads();

    // 2. combine 16 partial keys for channel c = tid -> winner -> LDS hist
    {
        u64 bestk = 0;
        const u64* pk = pkeys + (size_t)b * NCH * CC + tid;
        #pragma unroll
        for (int k = 0; k < NCH; ++k) {
            u64 key = pk[k * CC];
            bestk = (key > bestk) ? key : bestk;
        }
        int idx = 4095 - (int)(bestk & 0xFFFu);
        atomicAdd(&cnt[idx], 1);
    }
    __syncthreads();

    // 3. write counts (coalesced float4) + per-chunk hist (wave w <-> chunk w)
    {
        float4 cf;
        cf.x = (float)cnt[4 * tid + 0];
        cf.y = (float)cnt[4 * tid + 1];
        cf.z = (float)cnt[4 * tid + 2];
        cf.w = (float)cnt[4 * tid + 3];
        *(float4*)(counts + (size_t)b * NN + 4 * tid) = cf;

        int h0 = 0, h1 = 0;
        #pragma unroll
        for (int r = 0; r < 4; ++r) {
            int ci = cnt[wv * CHK + r * 64 + lane];
            u64 m0 = __ballot(ci == 0);
            u64 m1 = __ballot(ci == 1);
            if (lane == 0) { h0 += (int)__popcll(m0); h1 += (int)__popcll(m1); }
            if (ci > 1) atomicAdd(&H[wv * (CC + 1) + ci], 1);
        }
        if (lane == 0) {           // bins 0/1 never touched by the atomics
            H[wv * (CC + 1) + 0] = h0;
            H[wv * (CC + 1) + 1] = h1;
        }
    }
    __syncthreads();

    // 4. transform H[w][v] -> prefix over chunks (per value v=tid); row total
    //    g_v; entropy partial; wave-level shuffle scan + reduce (no barriers)
    int g_v, run1024 = 0;
    {
        int run = 0;
        #pragma unroll
        for (int w = 0; w < NCH; ++w) {
            int t = H[w * (CC + 1) + tid];
            H[w * (CC + 1) + tid] = run;     // prefix of chunks < w
            run += t;
        }
        g_v = run;
        if (tid == 0) {                      // value bin 1024 handled by thread 0
            int run2 = 0;
            #pragma unroll
            for (int w = 0; w < NCH; ++w) {
                int t = H[w * (CC + 1) + CC];
                H[w * (CC + 1) + CC] = run2;
                run2 += t;
            }
            run1024 = run2;
        }
    }
    const float S = 1024.0f + 4096.0f * 1e-6f;   // sum(counts)+N*eps exactly
    float e = 0.f;
    if (g_v) {
        float p = ((float)tid + 1e-6f) / S;
        e = (float)g_v * p * log2f(p);
    }
    if (tid == 0 && run1024) {
        float p = (1024.0f + 1e-6f) / S;
        e += (float)run1024 * p * log2f(p);
    }
    int incl = g_v;                              // wave inclusive scan
    #pragma unroll
    for (int d = 1; d < 64; d <<= 1) {
        int t = __shfl_up(incl, d, 64);
        if (lane >= d) incl += t;
    }
    float er = e;                                // wave entropy reduce
    #pragma unroll
    for (int d = 32; d > 0; d >>= 1)
        er += __shfl_down(er, d, 64);
    if (lane == 63) wsum[wv] = incl;
    if (lane == 0)  esum[wv] = er;
    __syncthreads();

    // 5. wave0: exclusive scan of 16 wave sums; wave1: entropy total -> ent[b]
    if (wv == 0) {
        int v = (lane < 16) ? wsum[lane] : 0;
        int inc2 = v;
        #pragma unroll
        for (int d = 1; d < 16; d <<= 1) {
            int t = __shfl_up(inc2, d, 64);
            if (lane >= d) inc2 += t;
        }
        if (lane < 16) wsum[lane] = inc2 - v;    // exclusive wave prefix
    } else if (wv == 1) {
        float v = (lane < 16) ? esum[lane] : 0.f;
        #pragma unroll
        for (int d = 8; d > 0; d >>= 1)
            v += __shfl_down(v, d, 64);
        if (lane == 0) ent[b] = -v / 12.0f;      // log2(4096) = 12
    }
    __syncthreads();

    // 6. exclusive value prefix -> LDS
    exvs[tid] = incl - g_v + wsum[wv];
    if (tid == 0) exvs[CC] = NN - run1024;
    __syncthreads();

    // 7. stable placement: wave w <-> chunk w; 4 batches of 64 points in index
    //    order. Rank among equals within batch via match-any ballot; rank
    //    across batches via per-(chunk,value) cursor in H (wave-private row).
    {
        const u64 ltmask = (1ull << lane) - 1ull;
        int* curw = &H[wv * (CC + 1)];
        float* orow = imp2 + (size_t)b * NN;
        for (int r = 0; r < 4; ++r) {
            const int n = wv * CHK + r * 64 + lane;
            const int ci = cnt[n];
            // match-any: eq = mask of lanes whose ci equals mine
            u64 eq = 0, todo = ~0ull;
            while (true) {                        // ~#distinct values iterations
                int src = (int)__builtin_ctzll(todo);
                int v0 = __shfl(ci, src, 64);
                u64 m = __ballot(ci == v0);
                if (ci == v0) eq = m;
                todo &= ~m;
                if (todo == 0ull) break;
            }
            int rank = (int)__popcll(eq & ltmask);
            int c0 = curw[ci];                    // broadcast-ish LDS read
            orow[c0 + exvs[ci] + rank] = (float)n;
            if ((eq >> lane) == 1ull)             // highest equal lane updates
                curw[ci] = c0 + (int)__popcll(eq);
        }
    }
}

extern "C" void kernel_launch(void* const* d_in, const int* in_sizes, int n_in,
                              void* d_out, int out_size, void* d_ws, size_t ws_size,
                              hipStream_t stream) {
    const float* x = (const float*)d_in[0];    // [32,3,4096]
    const float* W = (const float*)d_in[1];    // [1024,3]
    float* out    = (float*)d_out;
    float* out_x  = out;                        // 393216
    float* counts = out + (size_t)BB * 3 * NN;  // 131072
    float* imp2   = counts + (size_t)BB * NN;   // 131072
    float* ent    = imp2 + (size_t)BB * NN;     // 32

    u64* pkeys = (u64*)d_ws;                    // 32*16*1024 u64 = 4 MB

    k1_argmax_partial<<<BB * NCH, 256, 0, stream>>>(x, W, out_x, pkeys);
    k2_row_all<<<BB, 1024, 0, stream>>>(pkeys, counts, imp2, ent);
}